// Round 5
// baseline (718.424 us; speedup 1.0000x reference)
//
#include <hip/hip_runtime.h>
#include <hip/hip_bf16.h>

#define H 128
#define NFEAT 10
#define EFEAT 10
#define XPS 144   // packed xp row stride in bf16: 128 vals + 8 f32 scores

typedef __attribute__((ext_vector_type(8))) short bf16x8;
typedef __attribute__((ext_vector_type(4))) float f32x4;
typedef __attribute__((ext_vector_type(16))) float f32x16;
typedef __attribute__((ext_vector_type(4))) unsigned u32x4;
typedef __attribute__((ext_vector_type(2))) unsigned u32x2;

__device__ __forceinline__ float bflo(unsigned v) { return __uint_as_float(v << 16); }
__device__ __forceinline__ float bfhi(unsigned v) { return __uint_as_float(v & 0xffff0000u); }
__device__ __forceinline__ unsigned bfpack(float a, float b) {
    __hip_bfloat16 h0 = __float2bfloat16(a), h1 = __float2bfloat16(b);
    return (unsigned)(*(unsigned short*)&h0) | ((unsigned)(*(unsigned short*)&h1) << 16);
}
__device__ __forceinline__ bf16x8 cast8(u32x4 v) { return __builtin_bit_cast(bf16x8, v); }

// Next-GEMM B-fragment for 16-k step half b2, directly from 8 acc-order packed
// words (no cross-lane ops). Weight prep labels its K-rows with the same
// slot->feature map: rel k = 4*hh + (j&3) + 8*(j>>2). Verified R3 (absmax 0.0156).
__device__ __forceinline__ bf16x8 frag_from_pack(const unsigned* w, int b2) {
    u32x4 t;
    t.x = w[b2 * 4 + 0];
    t.y = w[b2 * 4 + 1];
    t.z = w[b2 * 4 + 2];
    t.w = w[b2 * 4 + 3];
    return cast8(t);
}

// bias + LayerNorm + ReLU on NT 32x32 D-tiles (f32x16 each), then pack to
// acc-order bf16 words pk[m][p].
template<int NT>
__device__ __forceinline__ void bias_ln_relu_pack(f32x16* acc, const float* __restrict__ bias,
        const float* __restrict__ g, const float* __restrict__ beta,
        int hh, float invn, unsigned (*pk)[8]) {
    float sm = 0.f;
#pragma unroll
    for (int m = 0; m < NT; m++) {
#pragma unroll
        for (int P = 0; P < 4; P++) {
            f32x4 bv = *(const f32x4*)&bias[m * 32 + P * 8 + hh * 4];
#pragma unroll
            for (int u = 0; u < 4; u++) {
                float v = acc[m][P * 4 + u] + bv[u];
                acc[m][P * 4 + u] = v;
                sm += v;
            }
        }
    }
    sm += __shfl_xor(sm, 32, 64);
    float mean = sm * invn;
    float q = 0.f;
#pragma unroll
    for (int m = 0; m < NT; m++) {
#pragma unroll
        for (int r = 0; r < 16; r++) { float d = acc[m][r] - mean; q += d * d; }
    }
    q += __shfl_xor(q, 32, 64);
    float rstd = rsqrtf(q * invn + 1e-5f);
#pragma unroll
    for (int m = 0; m < NT; m++) {
#pragma unroll
        for (int P = 0; P < 4; P++) {
            f32x4 gv = *(const f32x4*)&g[m * 32 + P * 8 + hh * 4];
            f32x4 bz = *(const f32x4*)&beta[m * 32 + P * 8 + hh * 4];
#pragma unroll
            for (int u = 0; u < 4; u++) {
                float y = fmaxf((acc[m][P * 4 + u] - mean) * rstd * gv[u] + bz[u], 0.f);
                acc[m][P * 4 + u] = y;
            }
        }
    }
#pragma unroll
    for (int m = 0; m < NT; m++) {
#pragma unroll
        for (int p = 0; p < 8; p++) pk[m][p] = bfpack(acc[m][2 * p], acc[m][2 * p + 1]);
    }
}

// ---------------- CSR build ----------------
__global__ __launch_bounds__(256) void k_degree(const int* __restrict__ col,
                                                int* __restrict__ deg, int E, int N) {
    int i = blockIdx.x * blockDim.x + threadIdx.x;
    int E2 = E + N;
    if (i < E2) {
        int d = (i < E) ? col[i] : (i - E);
        atomicAdd(&deg[d], 1);
    }
}

__global__ __launch_bounds__(1024) void k_scan(const int* __restrict__ deg,
                                               int* __restrict__ offs,
                                               int* __restrict__ cursor, int N) {
    __shared__ int ps[1024];
    int t = threadIdx.x;
    int chunk = (N + 1023) / 1024;
    int begin = t * chunk;
    int end = begin + chunk; if (end > N) end = N;
    int s = 0;
    for (int i = begin; i < end; i++) s += deg[i];
    if (begin >= N) s = 0;
    ps[t] = s;
    __syncthreads();
    for (int off = 1; off < 1024; off <<= 1) {
        int v = (t >= off) ? ps[t - off] : 0;
        __syncthreads();
        ps[t] += v;
        __syncthreads();
    }
    int run = (t == 0) ? 0 : ps[t - 1];
    if (begin < N) {
        for (int i = begin; i < end; i++) {
            offs[i] = run;
            cursor[i] = run;
            run += deg[i];
        }
    }
    if (t == 1023) offs[N] = ps[1023];
}

__global__ __launch_bounds__(256) void k_scatter(const int* __restrict__ rowp,
                                                 const int* __restrict__ colp,
                                                 int* __restrict__ cursor,
                                                 int* __restrict__ srcs, int E, int N) {
    int i = blockIdx.x * blockDim.x + threadIdx.x;
    if (i < E + N) {
        int s, d;
        if (i < E) { s = rowp[i]; d = colp[i]; }
        else       { s = i - E;  d = i - E; }
        int pos = atomicAdd(&cursor[d], 1);
        srcs[pos] = s;
    }
}

// ---------------- Node encoder: 1 wave/node, lane = 2 features ----------------
__global__ __launch_bounds__(256) void k_node_enc(const float* __restrict__ x,
                                                  const float* __restrict__ wm,
                                                  const float* __restrict__ b,
                                                  const float* __restrict__ g,
                                                  const float* __restrict__ beta,
                                                  __hip_bfloat16* __restrict__ h, int N) {
    int t = threadIdx.x;
    int w = t >> 6, l = t & 63;
    int n = blockIdx.x * 4 + w;
    if (n >= N) return;
    float xs[NFEAT];
#pragma unroll
    for (int k = 0; k < NFEAT; k++) xs[k] = x[(size_t)n * NFEAT + k];
    float a0 = b[2 * l], a1 = b[2 * l + 1];
#pragma unroll
    for (int k = 0; k < NFEAT; k++) {
        float2 wv = *(const float2*)&wm[k * H + 2 * l];
        a0 += xs[k] * wv.x;
        a1 += xs[k] * wv.y;
    }
    float p = a0 + a1;
#pragma unroll
    for (int s = 1; s < 64; s <<= 1) p += __shfl_xor(p, s, 64);
    float mean = p * (1.0f / H);
    float d0 = a0 - mean, d1 = a1 - mean;
    float q = d0 * d0 + d1 * d1;
#pragma unroll
    for (int s = 1; s < 64; s <<= 1) q += __shfl_xor(q, s, 64);
    float rstd = rsqrtf(q * (1.0f / H) + 1e-5f);
    float y0 = fmaxf(d0 * rstd * g[2 * l] + beta[2 * l], 0.0f);
    float y1 = fmaxf(d1 * rstd * g[2 * l + 1] + beta[2 * l + 1], 0.0f);
    *(unsigned*)&h[(size_t)n * H + 2 * l] = bfpack(y0, y1);
}

// ---------------- GAT stage 1: MFMA xp = h@w, fused scores (packed rows) ----------------
__global__ __launch_bounds__(256, 2) void k_gat_xp_mfma(
        const __hip_bfloat16* __restrict__ h_bf,
        const __hip_bfloat16* __restrict__ wT,
        const float* __restrict__ asrc,
        const float* __restrict__ adst,
        __hip_bfloat16* __restrict__ xp_bf,
        float* __restrict__ a_d,
        int heads, int N) {
    __shared__ __hip_bfloat16 Ws[128 * 136];
    __shared__ __hip_bfloat16 As[64 * 136];
    int t = threadIdx.x;
    int n0 = blockIdx.x * 64;

#pragma unroll
    for (int it = 0; it < 2; it++) {
        int idx = it * 256 + t;
        int row = idx >> 2, seg = idx & 3;
        const uint4* src = (const uint4*)(wT + row * 128 + seg * 32);
        uint4 v0 = src[0], v1 = src[1], v2 = src[2], v3 = src[3];
        uint4* dst = (uint4*)&Ws[row * 136 + seg * 32];
        dst[0] = v0; dst[1] = v1; dst[2] = v2; dst[3] = v3;
    }
    {
        int row = t >> 2, seg = t & 3;
        int n = n0 + row; if (n >= N) n = N - 1;
        const uint4* src = (const uint4*)(h_bf + (size_t)n * 128 + seg * 32);
        uint4 v0 = src[0], v1 = src[1], v2 = src[2], v3 = src[3];
        uint4* dst = (uint4*)&As[row * 136 + seg * 32];
        dst[0] = v0; dst[1] = v1; dst[2] = v2; dst[3] = v3;
    }
    __syncthreads();

    int w = t >> 6, l = t & 63, ln15 = l & 15, quad = l >> 4, q8 = quad * 8;
    f32x4 acc[8] = {};
#pragma unroll
    for (int k = 0; k < 128; k += 32) {
        bf16x8 af = *(const bf16x8*)&As[(w * 16 + ln15) * 136 + k + q8];
#pragma unroll
        for (int i = 0; i < 8; i++) {
            bf16x8 bfr = *(const bf16x8*)&Ws[(i * 16 + ln15) * 136 + k + q8];
            acc[i] = __builtin_amdgcn_mfma_f32_16x16x32_bf16(af, bfr, acc[i], 0, 0, 0);
        }
    }

    if (heads == 8) {
#pragma unroll
        for (int i = 0; i < 8; i++) {
            float av = asrc[i * 16 + ln15], dvv = adst[i * 16 + ln15];
            float ps[4], pd[4];
#pragma unroll
            for (int r = 0; r < 4; r++) { ps[r] = acc[i][r] * av; pd[r] = acc[i][r] * dvv; }
#pragma unroll
            for (int s = 1; s < 16; s <<= 1) {
#pragma unroll
                for (int r = 0; r < 4; r++) {
                    ps[r] += __shfl_xor(ps[r], s, 64);
                    pd[r] += __shfl_xor(pd[r], s, 64);
                }
            }
            if (ln15 == 0) {
#pragma unroll
                for (int r = 0; r < 4; r++) {
                    int n = n0 + w * 16 + quad * 4 + r;
                    if (n < N) {
                        *(float*)&xp_bf[(size_t)n * XPS + 128 + 2 * i] = ps[r];
                        a_d[(size_t)n * 8 + i] = pd[r];
                    }
                }
            }
        }
    } else {
        float ps[4] = {0, 0, 0, 0}, pd[4] = {0, 0, 0, 0};
#pragma unroll
        for (int i = 0; i < 8; i++) {
            float av = asrc[i * 16 + ln15], dvv = adst[i * 16 + ln15];
#pragma unroll
            for (int r = 0; r < 4; r++) { ps[r] += acc[i][r] * av; pd[r] += acc[i][r] * dvv; }
        }
#pragma unroll
        for (int s = 1; s < 16; s <<= 1) {
#pragma unroll
            for (int r = 0; r < 4; r++) {
                ps[r] += __shfl_xor(ps[r], s, 64);
                pd[r] += __shfl_xor(pd[r], s, 64);
            }
        }
        if (ln15 == 0) {
#pragma unroll
            for (int r = 0; r < 4; r++) {
                int n = n0 + w * 16 + quad * 4 + r;
                if (n < N) {
                    *(float*)&xp_bf[(size_t)n * XPS + 128] = ps[r];
                    a_d[n] = pd[r];
                }
            }
        }
    }

#pragma unroll
    for (int i = 0; i < 8; i++) {
#pragma unroll
        for (int r = 0; r < 4; r++) {
            int n = n0 + w * 16 + quad * 4 + r;
            if (n < N) xp_bf[(size_t)n * XPS + i * 16 + ln15] = __float2bfloat16(acc[i][r]);
        }
    }
}

// ---------------- GAT stage 2: 1 wave/node, packed-row gather ----------------
__global__ __launch_bounds__(256) void k_gat_agg(const __hip_bfloat16* __restrict__ xp,
                                                 const float* __restrict__ a_d,
                                                 const int* __restrict__ offs,
                                                 const int* __restrict__ srcs,
                                                 const float* __restrict__ bias,
                                                 const float* __restrict__ g,
                                                 const float* __restrict__ b,
                                                 __hip_bfloat16* __restrict__ hout,
                                                 int heads, int N) {
    int t = threadIdx.x;
    int w = t >> 6, l = t & 63;
    int n = blockIdx.x * 4 + w;
    if (n >= N) return;
    int head = (heads == 8) ? (l >> 3) : 0;
    float adv = a_d[(size_t)n * heads + head];
    int s0 = offs[n], s1 = offs[n + 1];
    float acc0 = 0.0f, acc1 = 0.0f, den = 0.0f;
    int j = s0;
    for (; j + 4 <= s1; j += 4) {
        int s_[4];
#pragma unroll
        for (int u = 0; u < 4; u++) s_[u] = srcs[j + u];
        float e_[4]; unsigned v_[4];
#pragma unroll
        for (int u = 0; u < 4; u++) {
            const __hip_bfloat16* xr = xp + (size_t)s_[u] * XPS;
            e_[u] = ((const float*)xr)[64 + head];
            v_[u] = *(const unsigned*)&xr[2 * l];
        }
#pragma unroll
        for (int u = 0; u < 4; u++) {
            float e = e_[u] + adv;
            e = (e >= 0.0f) ? e : 0.2f * e;
            float ex = __expf(e);
            den += ex;
            acc0 += ex * bflo(v_[u]);
            acc1 += ex * bfhi(v_[u]);
        }
    }
    for (; j < s1; j++) {
        int s = srcs[j];
        const __hip_bfloat16* xr = xp + (size_t)s * XPS;
        float e = ((const float*)xr)[64 + head] + adv;
        e = (e >= 0.0f) ? e : 0.2f * e;
        float ex = __expf(e);
        den += ex;
        unsigned v = *(const unsigned*)&xr[2 * l];
        acc0 += ex * bflo(v);
        acc1 += ex * bfhi(v);
    }
    float inv = 1.0f / den;
    float v0 = acc0 * inv + bias[2 * l];
    float v1 = acc1 * inv + bias[2 * l + 1];
    float p = v0 + v1;
#pragma unroll
    for (int s = 1; s < 64; s <<= 1) p += __shfl_xor(p, s, 64);
    float mean = p * (1.0f / H);
    float d0 = v0 - mean, d1 = v1 - mean;
    float q = d0 * d0 + d1 * d1;
#pragma unroll
    for (int s = 1; s < 64; s <<= 1) q += __shfl_xor(q, s, 64);
    float rstd = rsqrtf(q * (1.0f / H) + 1e-5f);
    float y0 = fmaxf(d0 * rstd * g[2 * l] + b[2 * l], 0.0f);
    float y1 = fmaxf(d1 * rstd * g[2 * l + 1] + b[2 * l + 1], 0.0f);
    *(unsigned*)&hout[(size_t)n * H + 2 * l] = bfpack(y0, y1);
}

// ---------------- weight prep (R5) ----------------
// Regions (element index i):
//   [0,16384)      gef_sw : gate Ef-part, 32 frags, pack-sourced labels
//   [16384,32768)  c1s_sw : (W_c1S + W_c1D), 32 frags, pack-sourced labels
//   [32768,40960)  c2_sw  : 16 frags, pack-sourced labels
//   [40960,43008)  ee_sw  : 4 frags, memory-sourced labels (K pad 16)
//   [43008,92160)  wT3    : gatA[0], gatA[1], gatB in [n][k] layout
//   [92160,157696) wpre4  : W_gS, W_gD, W_c1S, W_c1D in [n][k] layout (for k_pre)
// Fragment layout: buf[(s*64+l)*8+j] = W[k][n], n = m*32+(l&31), s = ks*NMT+m.
// pack-sourced label: k = korig + 4*(l>>5) + (j&3) + 8*(j>>2)   (matches D-pack)
__global__ __launch_bounds__(256) void k_wprep(const float* __restrict__ gate_w,
                                               const float* __restrict__ c1_w,
                                               const float* __restrict__ c2_w,
                                               const float* __restrict__ gatA_w,
                                               const float* __restrict__ gatB_w,
                                               const float* __restrict__ ee_w,
                                               __hip_bfloat16* __restrict__ gef_sw,
                                               __hip_bfloat16* __restrict__ c1s_sw,
                                               __hip_bfloat16* __restrict__ c2_sw,
                                               __hip_bfloat16* __restrict__ ee_sw,
                                               __hip_bfloat16* __restrict__ wT3,
                                               __hip_bfloat16* __restrict__ wpre4) {
    int i = blockIdx.x * blockDim.x + threadIdx.x;
    if (i < 16384) {                       // gate Ef: 32 frags (NMT=4, KS=8)
        int j = i & 7, l = (i >> 3) & 63, s = i >> 9;
        int m = s & 3, ks = s >> 2;
        int k = 256 + ks * 16 + 4 * (l >> 5) + (j & 3) + 8 * (j >> 2);
        int n = m * 32 + (l & 31);
        gef_sw[i] = __float2bfloat16(gate_w[k * 128 + n]);
    } else if (i < 32768) {                // c1 sum: 32 frags (NMT=4, KS=8)
        int mm = i - 16384;
        int j = mm & 7, l = (mm >> 3) & 63, s = mm >> 9;
        int m = s & 3, ks = s >> 2;
        int k = ks * 16 + 4 * (l >> 5) + (j & 3) + 8 * (j >> 2);
        int n = m * 32 + (l & 31);
        c1s_sw[mm] = __float2bfloat16(c1_w[k * 128 + n] + c1_w[(128 + k) * 128 + n]);
    } else if (i < 40960) {                // c2: 16 frags (NMT=2, KS=8)
        int mm = i - 32768;
        int j = mm & 7, l = (mm >> 3) & 63, s = mm >> 9;
        int m = s & 1, ks = s >> 1;
        int k = ks * 16 + 4 * (l >> 5) + (j & 3) + 8 * (j >> 2);
        int n = m * 32 + (l & 31);
        c2_sw[mm] = __float2bfloat16(c2_w[k * 64 + n]);
    } else if (i < 43008) {                // ee: 4 frags (NMT=4, KS=1)
        int mm = i - 40960;
        int j = mm & 7, l = (mm >> 3) & 63, s = mm >> 9;
        int k = (l >> 5) * 8 + j;
        int n = s * 32 + (l & 31);
        ee_sw[mm] = (k < EFEAT) ? __float2bfloat16(ee_w[k * 128 + n]) : __float2bfloat16(0.0f);
    } else if (i < 92160) {                // gatA[0], gatA[1], gatB
        int mm = i - 43008;
        int mat = mm / 16384, r = mm % 16384;
        int n = r / 128, k = r % 128;
        const float* src = (mat < 2) ? (gatA_w + (size_t)mat * 16384) : gatB_w;
        wT3[mm] = __float2bfloat16(src[k * 128 + n]);
    } else if (i < 157696) {               // W_gS, W_gD, W_c1S, W_c1D
        int mm = i - 92160;
        int mat = mm / 16384, r = mm % 16384;
        int n = r / 128, k = r % 128;
        float v = (mat == 0) ? gate_w[k * 128 + n]
                : (mat == 1) ? gate_w[(128 + k) * 128 + n]
                : (mat == 2) ? c1_w[k * 128 + n]
                             : c1_w[(128 + k) * 128 + n];
        wpre4[mm] = __float2bfloat16(v);
    }
}

// ---------------- per-node precompute: pre[n] = [u | v | p | q] (f32, 512) ----
// u = W_gS.h, v = W_gD.h, p = W_c1S.h, q = W_c1D.h — each N x128x128 GEMM.
// Same verified GEMM core as k_gat_xp_mfma; blockIdx.y selects the matrix.
__global__ __launch_bounds__(256, 2) void k_pre_gemm(
        const __hip_bfloat16* __restrict__ h_bf,
        const __hip_bfloat16* __restrict__ wpre4,
        float* __restrict__ pre, int N) {
    __shared__ __hip_bfloat16 Ws[128 * 136];
    __shared__ __hip_bfloat16 As[64 * 136];
    int t = threadIdx.x;
    int n0 = blockIdx.x * 64;
    int mat = blockIdx.y;
    const __hip_bfloat16* wT = wpre4 + (size_t)mat * 16384;

#pragma unroll
    for (int it = 0; it < 2; it++) {
        int idx = it * 256 + t;
        int row = idx >> 2, seg = idx & 3;
        const uint4* src = (const uint4*)(wT + row * 128 + seg * 32);
        uint4 v0 = src[0], v1 = src[1], v2 = src[2], v3 = src[3];
        uint4* dst = (uint4*)&Ws[row * 136 + seg * 32];
        dst[0] = v0; dst[1] = v1; dst[2] = v2; dst[3] = v3;
    }
    {
        int row = t >> 2, seg = t & 3;
        int n = n0 + row; if (n >= N) n = N - 1;
        const uint4* src = (const uint4*)(h_bf + (size_t)n * 128 + seg * 32);
        uint4 v0 = src[0], v1 = src[1], v2 = src[2], v3 = src[3];
        uint4* dst = (uint4*)&As[row * 136 + seg * 32];
        dst[0] = v0; dst[1] = v1; dst[2] = v2; dst[3] = v3;
    }
    __syncthreads();

    int w = t >> 6, l = t & 63, ln15 = l & 15, quad = l >> 4, q8 = quad * 8;
    f32x4 acc[8] = {};
#pragma unroll
    for (int k = 0; k < 128; k += 32) {
        bf16x8 af = *(const bf16x8*)&As[(w * 16 + ln15) * 136 + k + q8];
#pragma unroll
        for (int i = 0; i < 8; i++) {
            bf16x8 bfr = *(const bf16x8*)&Ws[(i * 16 + ln15) * 136 + k + q8];
            acc[i] = __builtin_amdgcn_mfma_f32_16x16x32_bf16(af, bfr, acc[i], 0, 0, 0);
        }
    }
#pragma unroll
    for (int i = 0; i < 8; i++) {
#pragma unroll
        for (int r = 0; r < 4; r++) {
            int n = n0 + w * 16 + quad * 4 + r;
            if (n < N) pre[(size_t)n * 512 + mat * 128 + i * 16 + ln15] = acc[i][r];
        }
    }
}

// ---------------- Edge classifier v5: algebraic split, 32x32 MFMA ------------
// Per edge only the Ef-dependent GEMMs remain (84 MFMAs vs 180):
//   gate = sigmoid(W_gEf.Ef + u[src] + v[dst] + b)
//   c1in = (W_c1S+W_c1D).(g*Ef) + p[src] + q[dst]          (K=128, not 256)
// u,v,p,q are per-node f32 precomputes (k_pre_gemm) — the per-edge scattered
// bf16 h-row gathers and 96 of the MFMAs are gone. Live state ~145 VGPR ->
// __launch_bounds__(256,3) = 3 waves/SIMD (R2 lesson: demand must be < budget).
__global__ __launch_bounds__(256, 3) void k_edge_cls_v5(
        const int* __restrict__ rowp, const int* __restrict__ colp,
        const float* __restrict__ eattr,
        const float* __restrict__ pre,
        const __hip_bfloat16* __restrict__ ee_fa, const float* __restrict__ ee_b,
        const float* __restrict__ ee_g, const float* __restrict__ ee_beta,
        const __hip_bfloat16* __restrict__ gef_fa, const float* __restrict__ gate_b,
        const __hip_bfloat16* __restrict__ c1s_fa, const float* __restrict__ c1_b,
        const float* __restrict__ cl1_g, const float* __restrict__ cl1_b,
        const __hip_bfloat16* __restrict__ c2_fa, const float* __restrict__ c2_b,
        const float* __restrict__ cl2_g, const float* __restrict__ cl2_b,
        const float* __restrict__ c3_w, const float* __restrict__ c3_b,
        float* __restrict__ out, int E) {
    int t = threadIdx.x;
    int w = t >> 6, l = t & 63;
    int hh = l >> 5, e32 = l & 31;
    int eIdx = blockIdx.x * 128 + w * 32 + e32;
    int eF = (eIdx < E) ? eIdx : (E - 1);
    const float* pS = pre + (size_t)rowp[eF] * 512;
    const float* pD = pre + (size_t)colp[eF] * 512;

    // ---- GEMM0: Ef = relu(LN(ea @ ee_w + ee_b)), kept as packed words efw ----
    unsigned efw[4][8];
    {
        const char* eb = (const char*)(eattr + (size_t)eF * EFEAT);
        float2 p0 = *(const float2*)(eb + (hh << 5));
        float2 p1 = *(const float2*)(eb + 8);
        float2 p2 = *(const float2*)(eb + 16);
        float2 p3 = *(const float2*)(eb + 24);
        if (hh) { p1.x = p1.y = 0.f; p2.x = p2.y = 0.f; p3.x = p3.y = 0.f; }
        u32x4 bwv;
        bwv.x = bfpack(p0.x, p0.y);
        bwv.y = bfpack(p1.x, p1.y);
        bwv.z = bfpack(p2.x, p2.y);
        bwv.w = bfpack(p3.x, p3.y);
        bf16x8 bb = cast8(bwv);
        f32x16 acc[4] = {};
#pragma unroll
        for (int m = 0; m < 4; m++) {
            bf16x8 a = *(const bf16x8*)(ee_fa + ((size_t)m * 64 + l) * 8);
            acc[m] = __builtin_amdgcn_mfma_f32_32x32x16_bf16(a, bb, acc[m], 0, 0, 0);
        }
        bias_ln_relu_pack<4>(acc, ee_b, ee_g, ee_beta, hh, 1.f / 128.f, efw);
    }

    // ---- gate GEMM: acc1 = W_gEf . Ef  (K=128, 32 MFMAs) ----
    f32x16 acc1[4] = {};
    {
        bf16x8 af[4];
#pragma unroll
        for (int s = 0; s < 4; s++) af[s] = *(const bf16x8*)(gef_fa + ((size_t)s * 64 + l) * 8);
#pragma unroll
        for (int ks = 0; ks < 8; ks++) {
            bf16x8 bb = frag_from_pack(efw[ks >> 1], ks & 1);
#pragma unroll
            for (int mt = 0; mt < 4; mt++) {
                int s = ks * 4 + mt;
                bf16x8 a = af[s & 3];
                if (s + 4 < 32) af[s & 3] = *(const bf16x8*)(gef_fa + ((size_t)(s + 4) * 64 + l) * 8);
                acc1[mt] = __builtin_amdgcn_mfma_f32_32x32x16_bf16(a, bb, acc1[mt], 0, 0, 0);
            }
        }
    }

    // ---- gate epilogue: g = sigmoid(acc1 + u + v + b); gew = pack(g*Ef) ----
    unsigned gew[4][8];
    {
#pragma unroll
        for (int m = 0; m < 4; m++) {
#pragma unroll
            for (int P = 0; P < 4; P++) {
                int f0 = m * 32 + P * 8 + hh * 4;
                f32x4 gb = *(const f32x4*)&gate_b[f0];
                f32x4 uu = *(const f32x4*)(pS + f0);
                f32x4 vv = *(const f32x4*)(pD + 128 + f0);
#pragma unroll
                for (int u2 = 0; u2 < 2; u2++) {
                    int p = P * 2 + u2;
                    float g0 = acc1[m][2 * p]     + uu[2 * u2]     + vv[2 * u2]     + gb[2 * u2];
                    float g1 = acc1[m][2 * p + 1] + uu[2 * u2 + 1] + vv[2 * u2 + 1] + gb[2 * u2 + 1];
                    g0 = 1.f / (1.f + __expf(-g0));
                    g1 = 1.f / (1.f + __expf(-g1));
                    gew[m][p] = bfpack(g0 * bflo(efw[m][p]), g1 * bfhi(efw[m][p]));
                }
            }
        }
    }

    // ---- c1': acc2 = Wsum.(g*Ef) (K=128, 32 MFMAs) + p + q; LN; pack ----
    unsigned z1w[4][8];
    {
        f32x16 acc2[4] = {};
        bf16x8 af[4];
#pragma unroll
        for (int s = 0; s < 4; s++) af[s] = *(const bf16x8*)(c1s_fa + ((size_t)s * 64 + l) * 8);
#pragma unroll
        for (int ks = 0; ks < 8; ks++) {
            bf16x8 bb = frag_from_pack(gew[ks >> 1], ks & 1);
#pragma unroll
            for (int mt = 0; mt < 4; mt++) {
                int s = ks * 4 + mt;
                bf16x8 a = af[s & 3];
                if (s + 4 < 32) af[s & 3] = *(const bf16x8*)(c1s_fa + ((size_t)(s + 4) * 64 + l) * 8);
                acc2[mt] = __builtin_amdgcn_mfma_f32_32x32x16_bf16(a, bb, acc2[mt], 0, 0, 0);
            }
        }
#pragma unroll
        for (int m = 0; m < 4; m++) {
#pragma unroll
            for (int P = 0; P < 4; P++) {
                int f0 = m * 32 + P * 8 + hh * 4;
                f32x4 pp = *(const f32x4*)(pS + 256 + f0);
                f32x4 qq = *(const f32x4*)(pD + 384 + f0);
#pragma unroll
                for (int u = 0; u < 4; u++) acc2[m][P * 4 + u] += pp[u] + qq[u];
            }
        }
        bias_ln_relu_pack<4>(acc2, c1_b, cl1_g, cl1_b, hh, 1.f / 128.f, z1w);
    }

    // ---- GEMM3: z2 = relu(LN(z1 @ c2_w + b)); out = z2 @ c3_w + c3_b ----
    {
        f32x16 acc3[2] = {};
        bf16x8 af[4];
#pragma unroll
        for (int s = 0; s < 4; s++) af[s] = *(const bf16x8*)(c2_fa + ((size_t)s * 64 + l) * 8);
#pragma unroll
        for (int ks = 0; ks < 8; ks++) {
            bf16x8 bb = frag_from_pack(z1w[ks >> 1], ks & 1);
#pragma unroll
            for (int mt = 0; mt < 2; mt++) {
                int s = ks * 2 + mt;
                bf16x8 a = af[s & 3];
                if (s + 4 < 16) af[s & 3] = *(const bf16x8*)(c2_fa + ((size_t)(s + 4) * 64 + l) * 8);
                acc3[mt] = __builtin_amdgcn_mfma_f32_32x32x16_bf16(a, bb, acc3[mt], 0, 0, 0);
            }
        }
        // bias + LN(64) + relu + c3 dot
        float sm = 0.f;
#pragma unroll
        for (int m = 0; m < 2; m++) {
#pragma unroll
            for (int P = 0; P < 4; P++) {
                f32x4 bv = *(const f32x4*)&c2_b[m * 32 + P * 8 + hh * 4];
#pragma unroll
                for (int u = 0; u < 4; u++) {
                    float v = acc3[m][P * 4 + u] + bv[u];
                    acc3[m][P * 4 + u] = v;
                    sm += v;
                }
            }
        }
        sm += __shfl_xor(sm, 32, 64);
        float mean = sm * (1.f / 64.f);
        float q = 0.f;
#pragma unroll
        for (int m = 0; m < 2; m++) {
#pragma unroll
            for (int r = 0; r < 16; r++) { float d = acc3[m][r] - mean; q += d * d; }
        }
        q += __shfl_xor(q, 32, 64);
        float rstd = rsqrtf(q * (1.f / 64.f) + 1e-5f);
        float s0 = 0.f, s1 = 0.f;
#pragma unroll
        for (int m = 0; m < 2; m++) {
#pragma unroll
            for (int P = 0; P < 4; P++) {
                int f0 = m * 32 + P * 8 + hh * 4;
                f32x4 gv = *(const f32x4*)&cl2_g[f0];
                f32x4 bz = *(const f32x4*)&cl2_b[f0];
                f32x4 wA = *(const f32x4*)&c3_w[f0 * 2];
                f32x4 wB = *(const f32x4*)&c3_w[f0 * 2 + 4];
#pragma unroll
                for (int u = 0; u < 4; u++) {
                    float y = fmaxf((acc3[m][P * 4 + u] - mean) * rstd * gv[u] + bz[u], 0.f);
                    float wc0 = (u < 2) ? wA[2 * u] : wB[2 * u - 4];
                    float wc1 = (u < 2) ? wA[2 * u + 1] : wB[2 * u - 3];
                    s0 += y * wc0;
                    s1 += y * wc1;
                }
            }
        }
        s0 += __shfl_xor(s0, 32, 64);
        s1 += __shfl_xor(s1, 32, 64);
        if (hh == 0 && eIdx < E) {
            float2 o; o.x = s0 + c3_b[0]; o.y = s1 + c3_b[1];
            *(float2*)&out[(size_t)eIdx * 2] = o;
        }
    }
}

extern "C" void kernel_launch(void* const* d_in, const int* in_sizes, int n_in,
                              void* d_out, int out_size, void* d_ws, size_t ws_size,
                              hipStream_t stream) {
    const float* x        = (const float*)d_in[0];
    const int*   eidx     = (const int*)d_in[1];
    const float* eattr    = (const float*)d_in[2];
    const float* ne_w     = (const float*)d_in[3];
    const float* ne_b     = (const float*)d_in[4];
    const float* ne_g     = (const float*)d_in[5];
    const float* ne_beta  = (const float*)d_in[6];
    const float* ee_w     = (const float*)d_in[7];
    const float* ee_b     = (const float*)d_in[8];
    const float* ee_g     = (const float*)d_in[9];
    const float* ee_beta  = (const float*)d_in[10];
    const float* gate_w   = (const float*)d_in[11];
    const float* gate_b   = (const float*)d_in[12];
    const float* gatA_w   = (const float*)d_in[13];
    const float* gatA_as  = (const float*)d_in[14];
    const float* gatA_ad  = (const float*)d_in[15];
    const float* gatA_bias= (const float*)d_in[16];
    const float* gatB_w   = (const float*)d_in[17];
    const float* gatB_as  = (const float*)d_in[18];
    const float* gatB_ad  = (const float*)d_in[19];
    const float* gatB_bias= (const float*)d_in[20];
    const float* ln_g     = (const float*)d_in[21];
    const float* ln_b     = (const float*)d_in[22];
    const float* c1_w     = (const float*)d_in[23];
    const float* c1_b     = (const float*)d_in[24];
    const float* cl1_g    = (const float*)d_in[25];
    const float* cl1_b    = (const float*)d_in[26];
    const float* c2_w     = (const float*)d_in[27];
    const float* c2_b     = (const float*)d_in[28];
    const float* cl2_g    = (const float*)d_in[29];
    const float* cl2_b    = (const float*)d_in[30];
    const float* c3_w     = (const float*)d_in[31];
    const float* c3_b     = (const float*)d_in[32];

    const int N = in_sizes[0] / NFEAT;
    const int E = in_sizes[1] / 2;
    const int E2 = E + N;
    const int* rowp = eidx;
    const int* colp = eidx + E;

    char* ws = (char*)d_ws;
    size_t off = 0;
    auto alloc = [&](size_t bytes) -> void* {
        void* p = ws + off;
        off = (off + bytes + 255) & ~(size_t)255;
        return p;
    };
    int*   deg    = (int*)alloc((size_t)N * 4);
    int*   cursor = (int*)alloc((size_t)N * 4);
    int*   offs   = (int*)alloc((size_t)(N + 1) * 4);
    int*   srcs   = (int*)alloc((size_t)E2 * 4);
    float* a_d    = (float*)alloc((size_t)N * 8 * 4);
    __hip_bfloat16* h_bfA  = (__hip_bfloat16*)alloc((size_t)N * H * 2);
    __hip_bfloat16* h_bfB  = (__hip_bfloat16*)alloc((size_t)N * H * 2);
    __hip_bfloat16* xp_bf  = (__hip_bfloat16*)alloc((size_t)N * XPS * 2);
    __hip_bfloat16* gef_sw = (__hip_bfloat16*)alloc((size_t)16384 * 2);
    __hip_bfloat16* c1s_sw = (__hip_bfloat16*)alloc((size_t)16384 * 2);
    __hip_bfloat16* c2_sw  = (__hip_bfloat16*)alloc((size_t)8192 * 2);
    __hip_bfloat16* ee_sw  = (__hip_bfloat16*)alloc((size_t)2048 * 2);
    __hip_bfloat16* wT3    = (__hip_bfloat16*)alloc((size_t)3 * 128 * 128 * 2);
    __hip_bfloat16* wpre4  = (__hip_bfloat16*)alloc((size_t)4 * 128 * 128 * 2);
    float*          pre    = (float*)alloc((size_t)N * 512 * 4);
    (void)ws_size;

    // weight prep (157696 elements total)
    k_wprep<<<(157696 + 255) / 256, 256, 0, stream>>>(gate_w, c1_w, c2_w, gatA_w, gatB_w, ee_w,
                                                      gef_sw, c1s_sw, c2_sw, ee_sw, wT3, wpre4);

    // CSR build
    hipMemsetAsync(deg, 0, (size_t)N * 4, stream);
    k_degree<<<(E2 + 255) / 256, 256, 0, stream>>>(colp, deg, E, N);
    k_scan<<<1, 1024, 0, stream>>>(deg, offs, cursor, N);
    k_scatter<<<(E2 + 255) / 256, 256, 0, stream>>>(rowp, colp, cursor, srcs, E, N);

    // node encoder -> bf16
    int ngrid = (N + 3) / 4;
    k_node_enc<<<ngrid, 256, 0, stream>>>(x, ne_w, ne_b, ne_g, ne_beta, h_bfA, N);

    int xpgrid = (N + 63) / 64;
    __hip_bfloat16* hin = h_bfA;
    __hip_bfloat16* hout = h_bfB;
    for (int l = 0; l < 2; l++) {
        k_gat_xp_mfma<<<xpgrid, 256, 0, stream>>>(hin, wT3 + (size_t)l * 16384,
                                                  gatA_as + l * H, gatA_ad + l * H,
                                                  xp_bf, a_d, 8, N);
        k_gat_agg<<<ngrid, 256, 0, stream>>>(xp_bf, a_d, offs, srcs,
                                             gatA_bias + l * H, ln_g + l * H, ln_b + l * H,
                                             hout, 8, N);
        __hip_bfloat16* tmp = hin; hin = hout; hout = tmp;
    }
    k_gat_xp_mfma<<<xpgrid, 256, 0, stream>>>(hin, wT3 + (size_t)2 * 16384,
                                              gatB_as, gatB_ad,
                                              xp_bf, a_d, 1, N);
    k_gat_agg<<<ngrid, 256, 0, stream>>>(xp_bf, a_d, offs, srcs,
                                         gatB_bias, ln_g + 2 * H, ln_b + 2 * H,
                                         hout, 1, N);

    // per-node precompute: pre[n] = [W_gS.h | W_gD.h | W_c1S.h | W_c1D.h] (f32)
    dim3 gpre(xpgrid, 4);
    k_pre_gemm<<<gpre, 256, 0, stream>>>(hout, wpre4, pre, N);

    // algebraic-split edge classifier
    k_edge_cls_v5<<<(E + 127) / 128, 256, 0, stream>>>(
        rowp, colp, eattr, pre,
        ee_sw, ee_b, ee_g, ee_beta,
        gef_sw, gate_b,
        c1s_sw, c1_b, cl1_g, cl1_b,
        c2_sw, c2_b, cl2_g, cl2_b,
        c3_w, c3_b,
        (float*)d_out, E);
}

// Round 6
// 690.955 us; speedup vs baseline: 1.0398x; 1.0398x over previous
//
#include <hip/hip_runtime.h>
#include <hip/hip_bf16.h>

#define H 128
#define NFEAT 10
#define EFEAT 10
#define XPS 144   // packed xp row stride in bf16: 128 vals + 8 f32 scores

typedef __attribute__((ext_vector_type(8))) short bf16x8;
typedef __attribute__((ext_vector_type(4))) float f32x4;
typedef __attribute__((ext_vector_type(16))) float f32x16;
typedef __attribute__((ext_vector_type(4))) unsigned u32x4;
typedef __attribute__((ext_vector_type(2))) unsigned u32x2;

__device__ __forceinline__ float bflo(unsigned v) { return __uint_as_float(v << 16); }
__device__ __forceinline__ float bfhi(unsigned v) { return __uint_as_float(v & 0xffff0000u); }
__device__ __forceinline__ unsigned bfpack(float a, float b) {
    __hip_bfloat16 h0 = __float2bfloat16(a), h1 = __float2bfloat16(b);
    return (unsigned)(*(unsigned short*)&h0) | ((unsigned)(*(unsigned short*)&h1) << 16);
}
__device__ __forceinline__ bf16x8 cast8(u32x4 v) { return __builtin_bit_cast(bf16x8, v); }

// Next-GEMM B-fragment for 16-k step half b2, directly from 8 acc-order packed
// words (no cross-lane ops). Weight prep labels its K-rows with the same
// slot->feature map: rel k = 4*hh + (j&3) + 8*(j>>2). Verified R3 (absmax 0.0156).
__device__ __forceinline__ bf16x8 frag_from_pack(const unsigned* w, int b2) {
    u32x4 t;
    t.x = w[b2 * 4 + 0];
    t.y = w[b2 * 4 + 1];
    t.z = w[b2 * 4 + 2];
    t.w = w[b2 * 4 + 3];
    return cast8(t);
}

// bias + LayerNorm + ReLU on NT 32x32 D-tiles (f32x16 each), then pack to
// acc-order bf16 words pk[m][p].
template<int NT>
__device__ __forceinline__ void bias_ln_relu_pack(f32x16* acc, const float* __restrict__ bias,
        const float* __restrict__ g, const float* __restrict__ beta,
        int hh, float invn, unsigned (*pk)[8]) {
    float sm = 0.f;
#pragma unroll
    for (int m = 0; m < NT; m++) {
#pragma unroll
        for (int P = 0; P < 4; P++) {
            f32x4 bv = *(const f32x4*)&bias[m * 32 + P * 8 + hh * 4];
#pragma unroll
            for (int u = 0; u < 4; u++) {
                float v = acc[m][P * 4 + u] + bv[u];
                acc[m][P * 4 + u] = v;
                sm += v;
            }
        }
    }
    sm += __shfl_xor(sm, 32, 64);
    float mean = sm * invn;
    float q = 0.f;
#pragma unroll
    for (int m = 0; m < NT; m++) {
#pragma unroll
        for (int r = 0; r < 16; r++) { float d = acc[m][r] - mean; q += d * d; }
    }
    q += __shfl_xor(q, 32, 64);
    float rstd = rsqrtf(q * invn + 1e-5f);
#pragma unroll
    for (int m = 0; m < NT; m++) {
#pragma unroll
        for (int P = 0; P < 4; P++) {
            f32x4 gv = *(const f32x4*)&g[m * 32 + P * 8 + hh * 4];
            f32x4 bz = *(const f32x4*)&beta[m * 32 + P * 8 + hh * 4];
#pragma unroll
            for (int u = 0; u < 4; u++) {
                float y = fmaxf((acc[m][P * 4 + u] - mean) * rstd * gv[u] + bz[u], 0.f);
                acc[m][P * 4 + u] = y;
            }
        }
    }
#pragma unroll
    for (int m = 0; m < NT; m++) {
#pragma unroll
        for (int p = 0; p < 8; p++) pk[m][p] = bfpack(acc[m][2 * p], acc[m][2 * p + 1]);
    }
}

// ---------------- CSR build ----------------
__global__ __launch_bounds__(256) void k_degree(const int* __restrict__ col,
                                                int* __restrict__ deg, int E, int N) {
    int i = blockIdx.x * blockDim.x + threadIdx.x;
    int E2 = E + N;
    if (i < E2) {
        int d = (i < E) ? col[i] : (i - E);
        atomicAdd(&deg[d], 1);
    }
}

__global__ __launch_bounds__(1024) void k_scan(const int* __restrict__ deg,
                                               int* __restrict__ offs,
                                               int* __restrict__ cursor, int N) {
    __shared__ int ps[1024];
    int t = threadIdx.x;
    int chunk = (N + 1023) / 1024;
    int begin = t * chunk;
    int end = begin + chunk; if (end > N) end = N;
    int s = 0;
    for (int i = begin; i < end; i++) s += deg[i];
    if (begin >= N) s = 0;
    ps[t] = s;
    __syncthreads();
    for (int off = 1; off < 1024; off <<= 1) {
        int v = (t >= off) ? ps[t - off] : 0;
        __syncthreads();
        ps[t] += v;
        __syncthreads();
    }
    int run = (t == 0) ? 0 : ps[t - 1];
    if (begin < N) {
        for (int i = begin; i < end; i++) {
            offs[i] = run;
            cursor[i] = run;
            run += deg[i];
        }
    }
    if (t == 1023) offs[N] = ps[1023];
}

__global__ __launch_bounds__(256) void k_scatter(const int* __restrict__ rowp,
                                                 const int* __restrict__ colp,
                                                 int* __restrict__ cursor,
                                                 int* __restrict__ srcs, int E, int N) {
    int i = blockIdx.x * blockDim.x + threadIdx.x;
    if (i < E + N) {
        int s, d;
        if (i < E) { s = rowp[i]; d = colp[i]; }
        else       { s = i - E;  d = i - E; }
        int pos = atomicAdd(&cursor[d], 1);
        srcs[pos] = s;
    }
}

// ---------------- Node encoder: 1 wave/node, lane = 2 features ----------------
__global__ __launch_bounds__(256) void k_node_enc(const float* __restrict__ x,
                                                  const float* __restrict__ wm,
                                                  const float* __restrict__ b,
                                                  const float* __restrict__ g,
                                                  const float* __restrict__ beta,
                                                  __hip_bfloat16* __restrict__ h, int N) {
    int t = threadIdx.x;
    int w = t >> 6, l = t & 63;
    int n = blockIdx.x * 4 + w;
    if (n >= N) return;
    float xs[NFEAT];
#pragma unroll
    for (int k = 0; k < NFEAT; k++) xs[k] = x[(size_t)n * NFEAT + k];
    float a0 = b[2 * l], a1 = b[2 * l + 1];
#pragma unroll
    for (int k = 0; k < NFEAT; k++) {
        float2 wv = *(const float2*)&wm[k * H + 2 * l];
        a0 += xs[k] * wv.x;
        a1 += xs[k] * wv.y;
    }
    float p = a0 + a1;
#pragma unroll
    for (int s = 1; s < 64; s <<= 1) p += __shfl_xor(p, s, 64);
    float mean = p * (1.0f / H);
    float d0 = a0 - mean, d1 = a1 - mean;
    float q = d0 * d0 + d1 * d1;
#pragma unroll
    for (int s = 1; s < 64; s <<= 1) q += __shfl_xor(q, s, 64);
    float rstd = rsqrtf(q * (1.0f / H) + 1e-5f);
    float y0 = fmaxf(d0 * rstd * g[2 * l] + beta[2 * l], 0.0f);
    float y1 = fmaxf(d1 * rstd * g[2 * l + 1] + beta[2 * l + 1], 0.0f);
    *(unsigned*)&h[(size_t)n * H + 2 * l] = bfpack(y0, y1);
}

// ---------------- GAT stage 1: MFMA xp = h@w, fused scores (packed rows) ----------------
__global__ __launch_bounds__(256, 2) void k_gat_xp_mfma(
        const __hip_bfloat16* __restrict__ h_bf,
        const __hip_bfloat16* __restrict__ wT,
        const float* __restrict__ asrc,
        const float* __restrict__ adst,
        __hip_bfloat16* __restrict__ xp_bf,
        float* __restrict__ a_d,
        int heads, int N) {
    __shared__ __hip_bfloat16 Ws[128 * 136];
    __shared__ __hip_bfloat16 As[64 * 136];
    int t = threadIdx.x;
    int n0 = blockIdx.x * 64;

#pragma unroll
    for (int it = 0; it < 2; it++) {
        int idx = it * 256 + t;
        int row = idx >> 2, seg = idx & 3;
        const uint4* src = (const uint4*)(wT + row * 128 + seg * 32);
        uint4 v0 = src[0], v1 = src[1], v2 = src[2], v3 = src[3];
        uint4* dst = (uint4*)&Ws[row * 136 + seg * 32];
        dst[0] = v0; dst[1] = v1; dst[2] = v2; dst[3] = v3;
    }
    {
        int row = t >> 2, seg = t & 3;
        int n = n0 + row; if (n >= N) n = N - 1;
        const uint4* src = (const uint4*)(h_bf + (size_t)n * 128 + seg * 32);
        uint4 v0 = src[0], v1 = src[1], v2 = src[2], v3 = src[3];
        uint4* dst = (uint4*)&As[row * 136 + seg * 32];
        dst[0] = v0; dst[1] = v1; dst[2] = v2; dst[3] = v3;
    }
    __syncthreads();

    int w = t >> 6, l = t & 63, ln15 = l & 15, quad = l >> 4, q8 = quad * 8;
    f32x4 acc[8] = {};
#pragma unroll
    for (int k = 0; k < 128; k += 32) {
        bf16x8 af = *(const bf16x8*)&As[(w * 16 + ln15) * 136 + k + q8];
#pragma unroll
        for (int i = 0; i < 8; i++) {
            bf16x8 bfr = *(const bf16x8*)&Ws[(i * 16 + ln15) * 136 + k + q8];
            acc[i] = __builtin_amdgcn_mfma_f32_16x16x32_bf16(af, bfr, acc[i], 0, 0, 0);
        }
    }

    if (heads == 8) {
#pragma unroll
        for (int i = 0; i < 8; i++) {
            float av = asrc[i * 16 + ln15], dvv = adst[i * 16 + ln15];
            float ps[4], pd[4];
#pragma unroll
            for (int r = 0; r < 4; r++) { ps[r] = acc[i][r] * av; pd[r] = acc[i][r] * dvv; }
#pragma unroll
            for (int s = 1; s < 16; s <<= 1) {
#pragma unroll
                for (int r = 0; r < 4; r++) {
                    ps[r] += __shfl_xor(ps[r], s, 64);
                    pd[r] += __shfl_xor(pd[r], s, 64);
                }
            }
            if (ln15 == 0) {
#pragma unroll
                for (int r = 0; r < 4; r++) {
                    int n = n0 + w * 16 + quad * 4 + r;
                    if (n < N) {
                        *(float*)&xp_bf[(size_t)n * XPS + 128 + 2 * i] = ps[r];
                        a_d[(size_t)n * 8 + i] = pd[r];
                    }
                }
            }
        }
    } else {
        float ps[4] = {0, 0, 0, 0}, pd[4] = {0, 0, 0, 0};
#pragma unroll
        for (int i = 0; i < 8; i++) {
            float av = asrc[i * 16 + ln15], dvv = adst[i * 16 + ln15];
#pragma unroll
            for (int r = 0; r < 4; r++) { ps[r] += acc[i][r] * av; pd[r] += acc[i][r] * dvv; }
        }
#pragma unroll
        for (int s = 1; s < 16; s <<= 1) {
#pragma unroll
            for (int r = 0; r < 4; r++) {
                ps[r] += __shfl_xor(ps[r], s, 64);
                pd[r] += __shfl_xor(pd[r], s, 64);
            }
        }
        if (ln15 == 0) {
#pragma unroll
            for (int r = 0; r < 4; r++) {
                int n = n0 + w * 16 + quad * 4 + r;
                if (n < N) {
                    *(float*)&xp_bf[(size_t)n * XPS + 128] = ps[r];
                    a_d[n] = pd[r];
                }
            }
        }
    }

#pragma unroll
    for (int i = 0; i < 8; i++) {
#pragma unroll
        for (int r = 0; r < 4; r++) {
            int n = n0 + w * 16 + quad * 4 + r;
            if (n < N) xp_bf[(size_t)n * XPS + i * 16 + ln15] = __float2bfloat16(acc[i][r]);
        }
    }
}

// ---------------- GAT stage 2: 1 wave/node, packed-row gather ----------------
__global__ __launch_bounds__(256) void k_gat_agg(const __hip_bfloat16* __restrict__ xp,
                                                 const float* __restrict__ a_d,
                                                 const int* __restrict__ offs,
                                                 const int* __restrict__ srcs,
                                                 const float* __restrict__ bias,
                                                 const float* __restrict__ g,
                                                 const float* __restrict__ b,
                                                 __hip_bfloat16* __restrict__ hout,
                                                 int heads, int N) {
    int t = threadIdx.x;
    int w = t >> 6, l = t & 63;
    int n = blockIdx.x * 4 + w;
    if (n >= N) return;
    int head = (heads == 8) ? (l >> 3) : 0;
    float adv = a_d[(size_t)n * heads + head];
    int s0 = offs[n], s1 = offs[n + 1];
    float acc0 = 0.0f, acc1 = 0.0f, den = 0.0f;
    int j = s0;
    for (; j + 4 <= s1; j += 4) {
        int s_[4];
#pragma unroll
        for (int u = 0; u < 4; u++) s_[u] = srcs[j + u];
        float e_[4]; unsigned v_[4];
#pragma unroll
        for (int u = 0; u < 4; u++) {
            const __hip_bfloat16* xr = xp + (size_t)s_[u] * XPS;
            e_[u] = ((const float*)xr)[64 + head];
            v_[u] = *(const unsigned*)&xr[2 * l];
        }
#pragma unroll
        for (int u = 0; u < 4; u++) {
            float e = e_[u] + adv;
            e = (e >= 0.0f) ? e : 0.2f * e;
            float ex = __expf(e);
            den += ex;
            acc0 += ex * bflo(v_[u]);
            acc1 += ex * bfhi(v_[u]);
        }
    }
    for (; j < s1; j++) {
        int s = srcs[j];
        const __hip_bfloat16* xr = xp + (size_t)s * XPS;
        float e = ((const float*)xr)[64 + head] + adv;
        e = (e >= 0.0f) ? e : 0.2f * e;
        float ex = __expf(e);
        den += ex;
        unsigned v = *(const unsigned*)&xr[2 * l];
        acc0 += ex * bflo(v);
        acc1 += ex * bfhi(v);
    }
    float inv = 1.0f / den;
    float v0 = acc0 * inv + bias[2 * l];
    float v1 = acc1 * inv + bias[2 * l + 1];
    float p = v0 + v1;
#pragma unroll
    for (int s = 1; s < 64; s <<= 1) p += __shfl_xor(p, s, 64);
    float mean = p * (1.0f / H);
    float d0 = v0 - mean, d1 = v1 - mean;
    float q = d0 * d0 + d1 * d1;
#pragma unroll
    for (int s = 1; s < 64; s <<= 1) q += __shfl_xor(q, s, 64);
    float rstd = rsqrtf(q * (1.0f / H) + 1e-5f);
    float y0 = fmaxf(d0 * rstd * g[2 * l] + b[2 * l], 0.0f);
    float y1 = fmaxf(d1 * rstd * g[2 * l + 1] + b[2 * l + 1], 0.0f);
    *(unsigned*)&hout[(size_t)n * H + 2 * l] = bfpack(y0, y1);
}

// ---------------- weight prep (R6 == R5 layout) ----------------
__global__ __launch_bounds__(256) void k_wprep(const float* __restrict__ gate_w,
                                               const float* __restrict__ c1_w,
                                               const float* __restrict__ c2_w,
                                               const float* __restrict__ gatA_w,
                                               const float* __restrict__ gatB_w,
                                               const float* __restrict__ ee_w,
                                               __hip_bfloat16* __restrict__ gef_sw,
                                               __hip_bfloat16* __restrict__ c1s_sw,
                                               __hip_bfloat16* __restrict__ c2_sw,
                                               __hip_bfloat16* __restrict__ ee_sw,
                                               __hip_bfloat16* __restrict__ wT3,
                                               __hip_bfloat16* __restrict__ wpre4) {
    int i = blockIdx.x * blockDim.x + threadIdx.x;
    if (i < 16384) {                       // gate Ef: 32 frags (NMT=4, KS=8)
        int j = i & 7, l = (i >> 3) & 63, s = i >> 9;
        int m = s & 3, ks = s >> 2;
        int k = 256 + ks * 16 + 4 * (l >> 5) + (j & 3) + 8 * (j >> 2);
        int n = m * 32 + (l & 31);
        gef_sw[i] = __float2bfloat16(gate_w[k * 128 + n]);
    } else if (i < 32768) {                // c1 sum: 32 frags (NMT=4, KS=8)
        int mm = i - 16384;
        int j = mm & 7, l = (mm >> 3) & 63, s = mm >> 9;
        int m = s & 3, ks = s >> 2;
        int k = ks * 16 + 4 * (l >> 5) + (j & 3) + 8 * (j >> 2);
        int n = m * 32 + (l & 31);
        c1s_sw[mm] = __float2bfloat16(c1_w[k * 128 + n] + c1_w[(128 + k) * 128 + n]);
    } else if (i < 40960) {                // c2: 16 frags (NMT=2, KS=8)
        int mm = i - 32768;
        int j = mm & 7, l = (mm >> 3) & 63, s = mm >> 9;
        int m = s & 1, ks = s >> 1;
        int k = ks * 16 + 4 * (l >> 5) + (j & 3) + 8 * (j >> 2);
        int n = m * 32 + (l & 31);
        c2_sw[mm] = __float2bfloat16(c2_w[k * 64 + n]);
    } else if (i < 43008) {                // ee: 4 frags (NMT=4, KS=1)
        int mm = i - 40960;
        int j = mm & 7, l = (mm >> 3) & 63, s = mm >> 9;
        int k = (l >> 5) * 8 + j;
        int n = s * 32 + (l & 31);
        ee_sw[mm] = (k < EFEAT) ? __float2bfloat16(ee_w[k * 128 + n]) : __float2bfloat16(0.0f);
    } else if (i < 92160) {                // gatA[0], gatA[1], gatB
        int mm = i - 43008;
        int mat = mm / 16384, r = mm % 16384;
        int n = r / 128, k = r % 128;
        const float* src = (mat < 2) ? (gatA_w + (size_t)mat * 16384) : gatB_w;
        wT3[mm] = __float2bfloat16(src[k * 128 + n]);
    } else if (i < 157696) {               // W_gS, W_gD, W_c1S, W_c1D
        int mm = i - 92160;
        int mat = mm / 16384, r = mm % 16384;
        int n = r / 128, k = r % 128;
        float v = (mat == 0) ? gate_w[k * 128 + n]
                : (mat == 1) ? gate_w[(128 + k) * 128 + n]
                : (mat == 2) ? c1_w[k * 128 + n]
                             : c1_w[(128 + k) * 128 + n];
        wpre4[mm] = __float2bfloat16(v);
    }
}

// ---------------- per-node precompute -> bf16, split by edge side ------------
// preS[n] = [u | p] (256 bf16), preD[n] = [v | q] (256 bf16).
// u = W_gS.h, v = W_gD.h, p = W_c1S.h, q = W_c1D.h. blockIdx.y = matrix.
// bf16 storage halves the per-edge gather bytes vs R5's f32 (the R5 regression).
__global__ __launch_bounds__(256, 2) void k_pre_gemm(
        const __hip_bfloat16* __restrict__ h_bf,
        const __hip_bfloat16* __restrict__ wpre4,
        __hip_bfloat16* __restrict__ preS,
        __hip_bfloat16* __restrict__ preD, int N) {
    __shared__ __hip_bfloat16 Ws[128 * 136];
    __shared__ __hip_bfloat16 As[64 * 136];
    int t = threadIdx.x;
    int n0 = blockIdx.x * 64;
    int mat = blockIdx.y;
    const __hip_bfloat16* wT = wpre4 + (size_t)mat * 16384;

#pragma unroll
    for (int it = 0; it < 2; it++) {
        int idx = it * 256 + t;
        int row = idx >> 2, seg = idx & 3;
        const uint4* src = (const uint4*)(wT + row * 128 + seg * 32);
        uint4 v0 = src[0], v1 = src[1], v2 = src[2], v3 = src[3];
        uint4* dst = (uint4*)&Ws[row * 136 + seg * 32];
        dst[0] = v0; dst[1] = v1; dst[2] = v2; dst[3] = v3;
    }
    {
        int row = t >> 2, seg = t & 3;
        int n = n0 + row; if (n >= N) n = N - 1;
        const uint4* src = (const uint4*)(h_bf + (size_t)n * 128 + seg * 32);
        uint4 v0 = src[0], v1 = src[1], v2 = src[2], v3 = src[3];
        uint4* dst = (uint4*)&As[row * 136 + seg * 32];
        dst[0] = v0; dst[1] = v1; dst[2] = v2; dst[3] = v3;
    }
    __syncthreads();

    int w = t >> 6, l = t & 63, ln15 = l & 15, quad = l >> 4, q8 = quad * 8;
    f32x4 acc[8] = {};
#pragma unroll
    for (int k = 0; k < 128; k += 32) {
        bf16x8 af = *(const bf16x8*)&As[(w * 16 + ln15) * 136 + k + q8];
#pragma unroll
        for (int i = 0; i < 8; i++) {
            bf16x8 bfr = *(const bf16x8*)&Ws[(i * 16 + ln15) * 136 + k + q8];
            acc[i] = __builtin_amdgcn_mfma_f32_16x16x32_bf16(af, bfr, acc[i], 0, 0, 0);
        }
    }
    __hip_bfloat16* base = (mat & 1) ? preD : preS;
    int off = (mat >> 1) * 128;
#pragma unroll
    for (int i = 0; i < 8; i++) {
#pragma unroll
        for (int r = 0; r < 4; r++) {
            int n = n0 + w * 16 + quad * 4 + r;
            if (n < N) base[(size_t)n * 256 + off + i * 16 + ln15] = __float2bfloat16(acc[i][r]);
        }
    }
}

// ---------------- Edge classifier v6: algebraic split, clean registers -------
// = R5 math with the two regressions fixed:
//  - __launch_bounds__(256,2): R5's (256,3) under-allocated (VGPR 84, 90 MB
//    spill WRITE). 256-reg budget >> demand -> spill-free (R3 precedent).
//  - preS/preD in bf16 split by side: 512 B gathered per edge side vs R5's
//    2 KB of f32 (FETCH 429 MB -> expect ~half).
__global__ __launch_bounds__(256, 2) void k_edge_cls_v6(
        const int* __restrict__ rowp, const int* __restrict__ colp,
        const float* __restrict__ eattr,
        const __hip_bfloat16* __restrict__ preS,
        const __hip_bfloat16* __restrict__ preD,
        const __hip_bfloat16* __restrict__ ee_fa, const float* __restrict__ ee_b,
        const float* __restrict__ ee_g, const float* __restrict__ ee_beta,
        const __hip_bfloat16* __restrict__ gef_fa, const float* __restrict__ gate_b,
        const __hip_bfloat16* __restrict__ c1s_fa, const float* __restrict__ c1_b,
        const float* __restrict__ cl1_g, const float* __restrict__ cl1_b,
        const __hip_bfloat16* __restrict__ c2_fa, const float* __restrict__ c2_b,
        const float* __restrict__ cl2_g, const float* __restrict__ cl2_b,
        const float* __restrict__ c3_w, const float* __restrict__ c3_b,
        float* __restrict__ out, int E) {
    int t = threadIdx.x;
    int w = t >> 6, l = t & 63;
    int hh = l >> 5, e32 = l & 31;
    int eIdx = blockIdx.x * 128 + w * 32 + e32;
    int eF = (eIdx < E) ? eIdx : (E - 1);
    const unsigned short* pS = (const unsigned short*)preS + (size_t)rowp[eF] * 256;
    const unsigned short* pD = (const unsigned short*)preD + (size_t)colp[eF] * 256;

    // ---- GEMM0: Ef = relu(LN(ea @ ee_w + ee_b)), kept as packed words efw ----
    unsigned efw[4][8];
    {
        const char* eb = (const char*)(eattr + (size_t)eF * EFEAT);
        float2 p0 = *(const float2*)(eb + (hh << 5));
        float2 p1 = *(const float2*)(eb + 8);
        float2 p2 = *(const float2*)(eb + 16);
        float2 p3 = *(const float2*)(eb + 24);
        if (hh) { p1.x = p1.y = 0.f; p2.x = p2.y = 0.f; p3.x = p3.y = 0.f; }
        u32x4 bwv;
        bwv.x = bfpack(p0.x, p0.y);
        bwv.y = bfpack(p1.x, p1.y);
        bwv.z = bfpack(p2.x, p2.y);
        bwv.w = bfpack(p3.x, p3.y);
        bf16x8 bb = cast8(bwv);
        f32x16 acc[4] = {};
#pragma unroll
        for (int m = 0; m < 4; m++) {
            bf16x8 a = *(const bf16x8*)(ee_fa + ((size_t)m * 64 + l) * 8);
            acc[m] = __builtin_amdgcn_mfma_f32_32x32x16_bf16(a, bb, acc[m], 0, 0, 0);
        }
        bias_ln_relu_pack<4>(acc, ee_b, ee_g, ee_beta, hh, 1.f / 128.f, efw);
    }

    // ---- gate GEMM: acc1 = W_gEf . Ef  (K=128, 32 MFMAs) ----
    f32x16 acc1[4] = {};
    {
        bf16x8 af[4];
#pragma unroll
        for (int s = 0; s < 4; s++) af[s] = *(const bf16x8*)(gef_fa + ((size_t)s * 64 + l) * 8);
#pragma unroll
        for (int ks = 0; ks < 8; ks++) {
            bf16x8 bb = frag_from_pack(efw[ks >> 1], ks & 1);
#pragma unroll
            for (int mt = 0; mt < 4; mt++) {
                int s = ks * 4 + mt;
                bf16x8 a = af[s & 3];
                if (s + 4 < 32) af[s & 3] = *(const bf16x8*)(gef_fa + ((size_t)(s + 4) * 64 + l) * 8);
                acc1[mt] = __builtin_amdgcn_mfma_f32_32x32x16_bf16(a, bb, acc1[mt], 0, 0, 0);
            }
        }
    }

    // ---- gate epilogue: g = sigmoid(acc1 + u + v + b); gew = pack(g*Ef) ----
    unsigned gew[4][8];
    {
#pragma unroll
        for (int m = 0; m < 4; m++) {
#pragma unroll
            for (int P = 0; P < 4; P++) {
                int f0 = m * 32 + P * 8 + hh * 4;
                f32x4 gb = *(const f32x4*)&gate_b[f0];
                u32x2 uw = *(const u32x2*)(pS + f0);
                u32x2 vw = *(const u32x2*)(pD + f0);
#pragma unroll
                for (int u2 = 0; u2 < 2; u2++) {
                    int p = P * 2 + u2;
                    unsigned uwd = u2 ? uw.y : uw.x;
                    unsigned vwd = u2 ? vw.y : vw.x;
                    float g0 = acc1[m][2 * p]     + bflo(uwd) + bflo(vwd) + gb[2 * u2];
                    float g1 = acc1[m][2 * p + 1] + bfhi(uwd) + bfhi(vwd) + gb[2 * u2 + 1];
                    g0 = 1.f / (1.f + __expf(-g0));
                    g1 = 1.f / (1.f + __expf(-g1));
                    gew[m][p] = bfpack(g0 * bflo(efw[m][p]), g1 * bfhi(efw[m][p]));
                }
            }
        }
    }

    // ---- c1': acc2 = Wsum.(g*Ef) (K=128, 32 MFMAs) + p + q; LN; pack ----
    unsigned z1w[4][8];
    {
        f32x16 acc2[4] = {};
        bf16x8 af[4];
#pragma unroll
        for (int s = 0; s < 4; s++) af[s] = *(const bf16x8*)(c1s_fa + ((size_t)s * 64 + l) * 8);
#pragma unroll
        for (int ks = 0; ks < 8; ks++) {
            bf16x8 bb = frag_from_pack(gew[ks >> 1], ks & 1);
#pragma unroll
            for (int mt = 0; mt < 4; mt++) {
                int s = ks * 4 + mt;
                bf16x8 a = af[s & 3];
                if (s + 4 < 32) af[s & 3] = *(const bf16x8*)(c1s_fa + ((size_t)(s + 4) * 64 + l) * 8);
                acc2[mt] = __builtin_amdgcn_mfma_f32_32x32x16_bf16(a, bb, acc2[mt], 0, 0, 0);
            }
        }
#pragma unroll
        for (int m = 0; m < 4; m++) {
#pragma unroll
            for (int P = 0; P < 4; P++) {
                int f0 = m * 32 + P * 8 + hh * 4;
                u32x2 pw = *(const u32x2*)(pS + 128 + f0);
                u32x2 qw = *(const u32x2*)(pD + 128 + f0);
                acc2[m][P * 4 + 0] += bflo(pw.x) + bflo(qw.x);
                acc2[m][P * 4 + 1] += bfhi(pw.x) + bfhi(qw.x);
                acc2[m][P * 4 + 2] += bflo(pw.y) + bflo(qw.y);
                acc2[m][P * 4 + 3] += bfhi(pw.y) + bfhi(qw.y);
            }
        }
        bias_ln_relu_pack<4>(acc2, c1_b, cl1_g, cl1_b, hh, 1.f / 128.f, z1w);
    }

    // ---- GEMM3: z2 = relu(LN(z1 @ c2_w + b)); out = z2 @ c3_w + c3_b ----
    {
        f32x16 acc3[2] = {};
        bf16x8 af[4];
#pragma unroll
        for (int s = 0; s < 4; s++) af[s] = *(const bf16x8*)(c2_fa + ((size_t)s * 64 + l) * 8);
#pragma unroll
        for (int ks = 0; ks < 8; ks++) {
            bf16x8 bb = frag_from_pack(z1w[ks >> 1], ks & 1);
#pragma unroll
            for (int mt = 0; mt < 2; mt++) {
                int s = ks * 2 + mt;
                bf16x8 a = af[s & 3];
                if (s + 4 < 16) af[s & 3] = *(const bf16x8*)(c2_fa + ((size_t)(s + 4) * 64 + l) * 8);
                acc3[mt] = __builtin_amdgcn_mfma_f32_32x32x16_bf16(a, bb, acc3[mt], 0, 0, 0);
            }
        }
        // bias + LN(64) + relu + c3 dot
        float sm = 0.f;
#pragma unroll
        for (int m = 0; m < 2; m++) {
#pragma unroll
            for (int P = 0; P < 4; P++) {
                f32x4 bv = *(const f32x4*)&c2_b[m * 32 + P * 8 + hh * 4];
#pragma unroll
                for (int u = 0; u < 4; u++) {
                    float v = acc3[m][P * 4 + u] + bv[u];
                    acc3[m][P * 4 + u] = v;
                    sm += v;
                }
            }
        }
        sm += __shfl_xor(sm, 32, 64);
        float mean = sm * (1.f / 64.f);
        float q = 0.f;
#pragma unroll
        for (int m = 0; m < 2; m++) {
#pragma unroll
            for (int r = 0; r < 16; r++) { float d = acc3[m][r] - mean; q += d * d; }
        }
        q += __shfl_xor(q, 32, 64);
        float rstd = rsqrtf(q * (1.f / 64.f) + 1e-5f);
        float s0 = 0.f, s1 = 0.f;
#pragma unroll
        for (int m = 0; m < 2; m++) {
#pragma unroll
            for (int P = 0; P < 4; P++) {
                int f0 = m * 32 + P * 8 + hh * 4;
                f32x4 gv = *(const f32x4*)&cl2_g[f0];
                f32x4 bz = *(const f32x4*)&cl2_b[f0];
                f32x4 wA = *(const f32x4*)&c3_w[f0 * 2];
                f32x4 wB = *(const f32x4*)&c3_w[f0 * 2 + 4];
#pragma unroll
                for (int u = 0; u < 4; u++) {
                    float y = fmaxf((acc3[m][P * 4 + u] - mean) * rstd * gv[u] + bz[u], 0.f);
                    float wc0 = (u < 2) ? wA[2 * u] : wB[2 * u - 4];
                    float wc1 = (u < 2) ? wA[2 * u + 1] : wB[2 * u - 3];
                    s0 += y * wc0;
                    s1 += y * wc1;
                }
            }
        }
        s0 += __shfl_xor(s0, 32, 64);
        s1 += __shfl_xor(s1, 32, 64);
        if (hh == 0 && eIdx < E) {
            float2 o; o.x = s0 + c3_b[0]; o.y = s1 + c3_b[1];
            *(float2*)&out[(size_t)eIdx * 2] = o;
        }
    }
}

extern "C" void kernel_launch(void* const* d_in, const int* in_sizes, int n_in,
                              void* d_out, int out_size, void* d_ws, size_t ws_size,
                              hipStream_t stream) {
    const float* x        = (const float*)d_in[0];
    const int*   eidx     = (const int*)d_in[1];
    const float* eattr    = (const float*)d_in[2];
    const float* ne_w     = (const float*)d_in[3];
    const float* ne_b     = (const float*)d_in[4];
    const float* ne_g     = (const float*)d_in[5];
    const float* ne_beta  = (const float*)d_in[6];
    const float* ee_w     = (const float*)d_in[7];
    const float* ee_b     = (const float*)d_in[8];
    const float* ee_g     = (const float*)d_in[9];
    const float* ee_beta  = (const float*)d_in[10];
    const float* gate_w   = (const float*)d_in[11];
    const float* gate_b   = (const float*)d_in[12];
    const float* gatA_w   = (const float*)d_in[13];
    const float* gatA_as  = (const float*)d_in[14];
    const float* gatA_ad  = (const float*)d_in[15];
    const float* gatA_bias= (const float*)d_in[16];
    const float* gatB_w   = (const float*)d_in[17];
    const float* gatB_as  = (const float*)d_in[18];
    const float* gatB_ad  = (const float*)d_in[19];
    const float* gatB_bias= (const float*)d_in[20];
    const float* ln_g     = (const float*)d_in[21];
    const float* ln_b     = (const float*)d_in[22];
    const float* c1_w     = (const float*)d_in[23];
    const float* c1_b     = (const float*)d_in[24];
    const float* cl1_g    = (const float*)d_in[25];
    const float* cl1_b    = (const float*)d_in[26];
    const float* c2_w     = (const float*)d_in[27];
    const float* c2_b     = (const float*)d_in[28];
    const float* cl2_g    = (const float*)d_in[29];
    const float* cl2_b    = (const float*)d_in[30];
    const float* c3_w     = (const float*)d_in[31];
    const float* c3_b     = (const float*)d_in[32];

    const int N = in_sizes[0] / NFEAT;
    const int E = in_sizes[1] / 2;
    const int E2 = E + N;
    const int* rowp = eidx;
    const int* colp = eidx + E;

    char* ws = (char*)d_ws;
    size_t off = 0;
    auto alloc = [&](size_t bytes) -> void* {
        void* p = ws + off;
        off = (off + bytes + 255) & ~(size_t)255;
        return p;
    };
    int*   deg    = (int*)alloc((size_t)N * 4);
    int*   cursor = (int*)alloc((size_t)N * 4);
    int*   offs   = (int*)alloc((size_t)(N + 1) * 4);
    int*   srcs   = (int*)alloc((size_t)E2 * 4);
    float* a_d    = (float*)alloc((size_t)N * 8 * 4);
    __hip_bfloat16* h_bfA  = (__hip_bfloat16*)alloc((size_t)N * H * 2);
    __hip_bfloat16* h_bfB  = (__hip_bfloat16*)alloc((size_t)N * H * 2);
    __hip_bfloat16* xp_bf  = (__hip_bfloat16*)alloc((size_t)N * XPS * 2);
    __hip_bfloat16* gef_sw = (__hip_bfloat16*)alloc((size_t)16384 * 2);
    __hip_bfloat16* c1s_sw = (__hip_bfloat16*)alloc((size_t)16384 * 2);
    __hip_bfloat16* c2_sw  = (__hip_bfloat16*)alloc((size_t)8192 * 2);
    __hip_bfloat16* ee_sw  = (__hip_bfloat16*)alloc((size_t)2048 * 2);
    __hip_bfloat16* wT3    = (__hip_bfloat16*)alloc((size_t)3 * 128 * 128 * 2);
    __hip_bfloat16* wpre4  = (__hip_bfloat16*)alloc((size_t)4 * 128 * 128 * 2);
    __hip_bfloat16* preS   = (__hip_bfloat16*)alloc((size_t)N * 256 * 2);
    __hip_bfloat16* preD   = (__hip_bfloat16*)alloc((size_t)N * 256 * 2);
    (void)ws_size;

    // weight prep (157696 elements total)
    k_wprep<<<(157696 + 255) / 256, 256, 0, stream>>>(gate_w, c1_w, c2_w, gatA_w, gatB_w, ee_w,
                                                      gef_sw, c1s_sw, c2_sw, ee_sw, wT3, wpre4);

    // CSR build
    hipMemsetAsync(deg, 0, (size_t)N * 4, stream);
    k_degree<<<(E2 + 255) / 256, 256, 0, stream>>>(colp, deg, E, N);
    k_scan<<<1, 1024, 0, stream>>>(deg, offs, cursor, N);
    k_scatter<<<(E2 + 255) / 256, 256, 0, stream>>>(rowp, colp, cursor, srcs, E, N);

    // node encoder -> bf16
    int ngrid = (N + 3) / 4;
    k_node_enc<<<ngrid, 256, 0, stream>>>(x, ne_w, ne_b, ne_g, ne_beta, h_bfA, N);

    int xpgrid = (N + 63) / 64;
    __hip_bfloat16* hin = h_bfA;
    __hip_bfloat16* hout = h_bfB;
    for (int l = 0; l < 2; l++) {
        k_gat_xp_mfma<<<xpgrid, 256, 0, stream>>>(hin, wT3 + (size_t)l * 16384,
                                                  gatA_as + l * H, gatA_ad + l * H,
                                                  xp_bf, a_d, 8, N);
        k_gat_agg<<<ngrid, 256, 0, stream>>>(xp_bf, a_d, offs, srcs,
                                             gatA_bias + l * H, ln_g + l * H, ln_b + l * H,
                                             hout, 8, N);
        __hip_bfloat16* tmp = hin; hin = hout; hout = tmp;
    }
    k_gat_xp_mfma<<<xpgrid, 256, 0, stream>>>(hin, wT3 + (size_t)2 * 16384,
                                              gatB_as, gatB_ad,
                                              xp_bf, a_d, 1, N);
    k_gat_agg<<<ngrid, 256, 0, stream>>>(xp_bf, a_d, offs, srcs,
                                         gatB_bias, ln_g + 2 * H, ln_b + 2 * H,
                                         hout, 1, N);

    // per-node precompute: preS = [W_gS.h | W_c1S.h], preD = [W_gD.h | W_c1D.h]
    dim3 gpre(xpgrid, 4);
    k_pre_gemm<<<gpre, 256, 0, stream>>>(hout, wpre4, preS, preD, N);

    // algebraic-split edge classifier (clean registers, bf16 pre)
    k_edge_cls_v6<<<(E + 127) / 128, 256, 0, stream>>>(
        rowp, colp, eattr, preS, preD,
        ee_sw, ee_b, ee_g, ee_beta,
        gef_sw, gate_b,
        c1s_sw, c1_b, cl1_g, cl1_b,
        c2_sw, c2_b, cl2_g, cl2_b,
        c3_w, c3_b,
        (float*)d_out, E);
}